// Round 1
// baseline (314.081 us; speedup 1.0000x reference)
//
#include <hip/hip_runtime.h>
#include <cstdint>

typedef __bf16 bf16x8 __attribute__((ext_vector_type(8)));
typedef float  f32x4  __attribute__((ext_vector_type(4)));

static constexpr int kB = 2, kT = 2048, kC = 1024, kH = 16, kD = 64;
static constexpr int kK = 1024;  // GEMM inner dim (= kC)

__device__ __forceinline__ uint16_t f2bf(float f) {
  uint32_t u = __builtin_bit_cast(uint32_t, f);
  u += 0x7FFFu + ((u >> 16) & 1u);
  return (uint16_t)(u >> 16);
}

__device__ __forceinline__ void gl_lds16(const void* g, void* l) {
  __builtin_amdgcn_global_load_lds((__attribute__((address_space(1))) void*)(void*)g,
                                   (__attribute__((address_space(3))) void*)l, 16, 0, 0);
}

// ---------------- prep: xp = bf16(x + pe), w casts ----------------
__global__ __launch_bounds__(256) void prep_xpe(const float* __restrict__ x,
                                                const float* __restrict__ pe,
                                                uint16_t* __restrict__ xp) {
  const int i = blockIdx.x * 256 + threadIdx.x;  // over B*T*C/4
  const float4 xv = ((const float4*)x)[i];
  const int c4 = i & (kC / 4 - 1);
  const int t = (i / (kC / 4)) & (kT - 1);
  const float4 pv = ((const float4*)pe)[t * (kC / 4) + c4];
  ushort4 o;
  o.x = f2bf(xv.x + pv.x);
  o.y = f2bf(xv.y + pv.y);
  o.z = f2bf(xv.z + pv.z);
  o.w = f2bf(xv.w + pv.w);
  ((ushort4*)xp)[i] = o;
}

__global__ __launch_bounds__(256) void cast_w(const float* __restrict__ w,
                                              uint16_t* __restrict__ o) {
  const int i = blockIdx.x * 256 + threadIdx.x;
  const float4 v = ((const float4*)w)[i];
  ushort4 u;
  u.x = f2bf(v.x); u.y = f2bf(v.y); u.z = f2bf(v.z); u.w = f2bf(v.w);
  ((ushort4*)o)[i] = u;
}

// ---------------- GEMM: C = A[M,K] * W[N,K]^T, bf16 MFMA ----------------
// 128x128 tile, 4 waves (2x2), BK=64, global_load_lds + XOR swizzle (G4/T2).
// EPI==0: qkv scatter (q,k -> [b,h,t,d] bf16; v -> [b,h,d,t] bf16)
// EPI==1: f32 row-major out
template <int EPI>
__global__ __launch_bounds__(256) void gemm_bt(const uint16_t* __restrict__ A,
                                               const uint16_t* __restrict__ W,
                                               uint16_t* __restrict__ qb,
                                               uint16_t* __restrict__ kb,
                                               uint16_t* __restrict__ vT,
                                               float* __restrict__ out) {
  __shared__ char lds[32768];  // A tile 16KB | B tile 16KB
  const int lane = threadIdx.x & 63;
  const int wid = threadIdx.x >> 6;
  const int l15 = lane & 15, l4 = lane >> 4;
  const int wm = wid >> 1, wn = wid & 1;
  const int m0 = blockIdx.x * 128, n0 = blockIdx.y * 128;

  f32x4 acc[4][4] = {};

  for (int k0 = 0; k0 < kK; k0 += 64) {
#pragma unroll
    for (int j = 0; j < 4; ++j) {
      const int off = wid * 4096 + j * 1024 + lane * 16;
      const int row = off >> 7;
      const int colb = (off & 127) ^ ((row & 7) << 4);  // inverse-swizzled source
      gl_lds16((const char*)A + ((size_t)(m0 + row) * kK + k0) * 2 + colb,
               lds + wid * 4096 + j * 1024);
      gl_lds16((const char*)W + ((size_t)(n0 + row) * kK + k0) * 2 + colb,
               lds + 16384 + wid * 4096 + j * 1024);
    }
    __syncthreads();
#pragma unroll
    for (int ks = 0; ks < 2; ++ks) {
      bf16x8 af[4], bf_[4];
#pragma unroll
      for (int mt = 0; mt < 4; ++mt) {
        const int r = wm * 64 + mt * 16 + l15;
        const int cb = (l4 * 16 + ks * 64) ^ ((r & 7) << 4);
        af[mt] = *(const bf16x8*)(lds + r * 128 + cb);
      }
#pragma unroll
      for (int nt = 0; nt < 4; ++nt) {
        const int r = wn * 64 + nt * 16 + l15;
        const int cb = (l4 * 16 + ks * 64) ^ ((r & 7) << 4);
        bf_[nt] = *(const bf16x8*)(lds + 16384 + r * 128 + cb);
      }
#pragma unroll
      for (int mt = 0; mt < 4; ++mt)
#pragma unroll
        for (int nt = 0; nt < 4; ++nt)
          acc[mt][nt] = __builtin_amdgcn_mfma_f32_16x16x32_bf16(af[mt], bf_[nt],
                                                                acc[mt][nt], 0, 0, 0);
    }
    __syncthreads();
  }

#pragma unroll
  for (int mt = 0; mt < 4; ++mt) {
#pragma unroll
    for (int nt = 0; nt < 4; ++nt) {
#pragma unroll
      for (int r = 0; r < 4; ++r) {
        const int m = m0 + wm * 64 + mt * 16 + l4 * 4 + r;
        const int n = n0 + wn * 64 + nt * 16 + l15;
        const float v = acc[mt][nt][r];
        if constexpr (EPI == 0) {
          const int b = m >> 11, t = m & (kT - 1);
          const int sec = n >> 10, nn = n & (kC - 1);
          const int h = nn >> 6, d = nn & 63;
          const size_t bh = (size_t)(b * kH + h);
          if (sec == 0)
            qb[(bh * kT + t) * kD + d] = f2bf(v);
          else if (sec == 1)
            kb[(bh * kT + t) * kD + d] = f2bf(v);
          else
            vT[(bh * kD + d) * kT + t] = f2bf(v);
        } else {
          out[(size_t)m * kC + n] = v;
        }
      }
    }
  }
}

// ---------------- flash attention (causal), 4 indep waves x 16 q-rows ----------------
__global__ __launch_bounds__(256) void attn(const uint16_t* __restrict__ qb,
                                            const uint16_t* __restrict__ kb,
                                            const uint16_t* __restrict__ vT,
                                            uint16_t* __restrict__ y) {
  __shared__ char plds[8192];  // 4 waves x 2KB P slab
  const int lane = threadIdx.x & 63;
  const int wid = threadIdx.x >> 6;
  const int l15 = lane & 15, l4 = lane >> 4;
  const int qt = blockIdx.x, bh = blockIdx.y;
  const int q0 = qt * 64 + wid * 16;  // this wave's first q row
  const size_t base = (size_t)bh * kT * kD;
  const uint16_t* Q = qb + base;
  const uint16_t* Kp = kb + base;
  const uint16_t* Vt = vT + base;
  char* P = plds + wid * 2048;

  // Q fragments (scaled by 1/sqrt(d))
  bf16x8 qf[2];
#pragma unroll
  for (int ks = 0; ks < 2; ++ks) {
    bf16x8 t = *(const bf16x8*)(Q + (size_t)(q0 + l15) * kD + ks * 32 + l4 * 8);
#pragma unroll
    for (int i = 0; i < 8; ++i) t[i] = (__bf16)((float)t[i] * 0.125f);
    qf[ks] = t;
  }

  float m[4], lsum[4];
  f32x4 o[4];
#pragma unroll
  for (int r = 0; r < 4; ++r) { m[r] = -1e30f; lsum[r] = 0.f; }
#pragma unroll
  for (int nt = 0; nt < 4; ++nt) o[nt] = (f32x4){0.f, 0.f, 0.f, 0.f};

  const int nkt = (q0 + 15) / 64 + 1;
  for (int kt = 0; kt < nkt; ++kt) {
    const int k0 = kt * 64;
    // S = Q K^T
    f32x4 s[4] = {};
#pragma unroll
    for (int ks = 0; ks < 2; ++ks) {
#pragma unroll
      for (int nt = 0; nt < 4; ++nt) {
        const bf16x8 kf =
            *(const bf16x8*)(Kp + (size_t)(k0 + nt * 16 + l15) * kD + ks * 32 + l4 * 8);
        s[nt] = __builtin_amdgcn_mfma_f32_16x16x32_bf16(qf[ks], kf, s[nt], 0, 0, 0);
      }
    }
    // causal mask (only the diagonal tile needs it)
    if (k0 + 63 > q0) {
#pragma unroll
      for (int nt = 0; nt < 4; ++nt) {
        const int kk = k0 + nt * 16 + l15;
#pragma unroll
        for (int r = 0; r < 4; ++r) {
          const int qq = q0 + l4 * 4 + r;
          if (kk > qq) s[nt][r] = -1e30f;
        }
      }
    }
    // online softmax (row lives across the 16 lanes of an l4-group)
    float scale[4];
#pragma unroll
    for (int r = 0; r < 4; ++r) {
      float mx = fmaxf(fmaxf(s[0][r], s[1][r]), fmaxf(s[2][r], s[3][r]));
      mx = fmaxf(mx, __shfl_xor(mx, 1));
      mx = fmaxf(mx, __shfl_xor(mx, 2));
      mx = fmaxf(mx, __shfl_xor(mx, 4));
      mx = fmaxf(mx, __shfl_xor(mx, 8));
      const float newm = fmaxf(m[r], mx);
      scale[r] = __expf(m[r] - newm);
      m[r] = newm;
      float ps = 0.f;
#pragma unroll
      for (int nt = 0; nt < 4; ++nt) {
        const float p = __expf(s[nt][r] - newm);
        s[nt][r] = p;
        ps += p;
      }
      ps += __shfl_xor(ps, 1);
      ps += __shfl_xor(ps, 2);
      ps += __shfl_xor(ps, 4);
      ps += __shfl_xor(ps, 8);
      lsum[r] = lsum[r] * scale[r] + ps;
    }
    // P -> LDS (bf16, XOR-swizzled), acc-layout -> A-frag-layout bounce
#pragma unroll
    for (int nt = 0; nt < 4; ++nt) {
#pragma unroll
      for (int r = 0; r < 4; ++r) {
        const int rp = l4 * 4 + r;
        const int cb = ((nt * 16 + l15) * 2) ^ ((rp & 7) << 4);
        *(uint16_t*)(P + rp * 128 + cb) = f2bf(s[nt][r]);
      }
    }
    asm volatile("s_waitcnt lgkmcnt(0)" ::: "memory");
    // rescale O
#pragma unroll
    for (int nt = 0; nt < 4; ++nt)
#pragma unroll
      for (int r = 0; r < 4; ++r) o[nt][r] *= scale[r];
    // O += P V
#pragma unroll
    for (int ks = 0; ks < 2; ++ks) {
      const int cb = (l4 * 16 + ks * 64) ^ ((l15 & 7) << 4);
      const bf16x8 pf = *(const bf16x8*)(P + l15 * 128 + cb);
#pragma unroll
      for (int nt = 0; nt < 4; ++nt) {
        const bf16x8 vf =
            *(const bf16x8*)(Vt + (size_t)(nt * 16 + l15) * kT + k0 + ks * 32 + l4 * 8);
        o[nt] = __builtin_amdgcn_mfma_f32_16x16x32_bf16(pf, vf, o[nt], 0, 0, 0);
      }
    }
  }
  // epilogue: y[b, q, h*64+d] bf16
  const int b = bh >> 4, h = bh & 15;
#pragma unroll
  for (int r = 0; r < 4; ++r) {
    const float inv = 1.0f / lsum[r];
    const int qq = q0 + l4 * 4 + r;
#pragma unroll
    for (int nt = 0; nt < 4; ++nt) {
      y[((size_t)(b * kT + qq)) * kC + h * kD + nt * 16 + l15] = f2bf(o[nt][r] * inv);
    }
  }
}

extern "C" void kernel_launch(void* const* d_in, const int* in_sizes, int n_in,
                              void* d_out, int out_size, void* d_ws, size_t ws_size,
                              hipStream_t stream) {
  const float* x = (const float*)d_in[0];
  const float* wqkv = (const float*)d_in[1];
  const float* wproj = (const float*)d_in[2];
  const float* pe = (const float*)d_in[3];

  char* ws = (char*)d_ws;
  uint16_t* xp = (uint16_t*)(ws);                          // 8MB, reused as y after QKV
  uint16_t* wq = (uint16_t*)(ws + (size_t)(8u << 20));     // 6MB
  uint16_t* wp = (uint16_t*)(ws + (size_t)(14u << 20));    // 2MB
  uint16_t* qbuf = (uint16_t*)(ws + (size_t)(16u << 20));  // 8MB
  uint16_t* kbuf = (uint16_t*)(ws + (size_t)(24u << 20));  // 8MB
  uint16_t* vTb = (uint16_t*)(ws + (size_t)(32u << 20));   // 8MB (total 40MB)

  prep_xpe<<<dim3(kB * kT * kC / 4 / 256), 256, 0, stream>>>(x, pe, xp);
  cast_w<<<dim3(3 * kC * kC / 4 / 256), 256, 0, stream>>>(wqkv, wq);
  cast_w<<<dim3(kC * kC / 4 / 256), 256, 0, stream>>>(wproj, wp);

  // qkv = xp @ wqkv^T : M=4096, N=3072
  gemm_bt<0><<<dim3(32, 24), 256, 0, stream>>>(xp, wq, qbuf, kbuf, vTb, nullptr);

  // attention -> y (stored into xp buffer, [B,T,C] bf16)
  attn<<<dim3(kT / 64, kB * kH), 256, 0, stream>>>(qbuf, kbuf, vTb, xp);

  // out = y @ wproj^T : M=4096, N=1024, f32 out
  gemm_bt<1><<<dim3(32, 8), 256, 0, stream>>>(xp, wp, nullptr, nullptr, nullptr,
                                              (float*)d_out);
}

// Round 2
// 222.236 us; speedup vs baseline: 1.4133x; 1.4133x over previous
//
#include <hip/hip_runtime.h>
#include <cstdint>

typedef __bf16 bf16x8 __attribute__((ext_vector_type(8)));
typedef __bf16 bf16x4 __attribute__((ext_vector_type(4)));
typedef float  f32x4  __attribute__((ext_vector_type(4)));

static constexpr int kB = 2, kT = 2048, kC = 1024, kH = 16, kD = 64;
static constexpr int kK = 1024;  // GEMM inner dim (= kC)

__device__ __forceinline__ uint16_t f2bf(float f) {
  uint32_t u = __builtin_bit_cast(uint32_t, f);
  u += 0x7FFFu + ((u >> 16) & 1u);
  return (uint16_t)(u >> 16);
}

__device__ __forceinline__ void gl_lds16(const void* g, void* l) {
  __builtin_amdgcn_global_load_lds((__attribute__((address_space(1))) void*)(void*)g,
                                   (__attribute__((address_space(3))) void*)l, 16, 0, 0);
}

// ---------------- prep: xp = bf16(x + pe), w casts ----------------
__global__ __launch_bounds__(256) void prep_xpe(const float* __restrict__ x,
                                                const float* __restrict__ pe,
                                                uint16_t* __restrict__ xp) {
  const int i = blockIdx.x * 256 + threadIdx.x;  // over B*T*C/4
  const float4 xv = ((const float4*)x)[i];
  const int c4 = i & (kC / 4 - 1);
  const int t = (i / (kC / 4)) & (kT - 1);
  const float4 pv = ((const float4*)pe)[t * (kC / 4) + c4];
  ushort4 o;
  o.x = f2bf(xv.x + pv.x);
  o.y = f2bf(xv.y + pv.y);
  o.z = f2bf(xv.z + pv.z);
  o.w = f2bf(xv.w + pv.w);
  ((ushort4*)xp)[i] = o;
}

__global__ __launch_bounds__(256) void cast_w(const float* __restrict__ w,
                                              uint16_t* __restrict__ o) {
  const int i = blockIdx.x * 256 + threadIdx.x;
  const float4 v = ((const float4*)w)[i];
  ushort4 u;
  u.x = f2bf(v.x); u.y = f2bf(v.y); u.z = f2bf(v.z); u.w = f2bf(v.w);
  ((ushort4*)o)[i] = u;
}

// ---------------- GEMM: C = A[M,K] * W[N,K]^T, bf16 MFMA ----------------
template <int EPI>
__global__ __launch_bounds__(256) void gemm_bt(const uint16_t* __restrict__ A,
                                               const uint16_t* __restrict__ W,
                                               uint16_t* __restrict__ qb,
                                               uint16_t* __restrict__ kb,
                                               uint16_t* __restrict__ vT,
                                               float* __restrict__ out) {
  __shared__ char lds[32768];  // A tile 16KB | B tile 16KB
  const int lane = threadIdx.x & 63;
  const int wid = threadIdx.x >> 6;
  const int l15 = lane & 15, l4 = lane >> 4;
  const int wm = wid >> 1, wn = wid & 1;
  const int m0 = blockIdx.x * 128, n0 = blockIdx.y * 128;

  f32x4 acc[4][4] = {};

  for (int k0 = 0; k0 < kK; k0 += 64) {
#pragma unroll
    for (int j = 0; j < 4; ++j) {
      const int off = wid * 4096 + j * 1024 + lane * 16;
      const int row = off >> 7;
      const int colb = (off & 127) ^ ((row & 7) << 4);  // inverse-swizzled source
      gl_lds16((const char*)A + ((size_t)(m0 + row) * kK + k0) * 2 + colb,
               lds + wid * 4096 + j * 1024);
      gl_lds16((const char*)W + ((size_t)(n0 + row) * kK + k0) * 2 + colb,
               lds + 16384 + wid * 4096 + j * 1024);
    }
    __syncthreads();
#pragma unroll
    for (int ks = 0; ks < 2; ++ks) {
      bf16x8 af[4], bf_[4];
#pragma unroll
      for (int mt = 0; mt < 4; ++mt) {
        const int r = wm * 64 + mt * 16 + l15;
        const int cb = (l4 * 16 + ks * 64) ^ ((r & 7) << 4);
        af[mt] = *(const bf16x8*)(lds + r * 128 + cb);
      }
#pragma unroll
      for (int nt = 0; nt < 4; ++nt) {
        const int r = wn * 64 + nt * 16 + l15;
        const int cb = (l4 * 16 + ks * 64) ^ ((r & 7) << 4);
        bf_[nt] = *(const bf16x8*)(lds + 16384 + r * 128 + cb);
      }
#pragma unroll
      for (int mt = 0; mt < 4; ++mt)
#pragma unroll
        for (int nt = 0; nt < 4; ++nt)
          acc[mt][nt] = __builtin_amdgcn_mfma_f32_16x16x32_bf16(af[mt], bf_[nt],
                                                                acc[mt][nt], 0, 0, 0);
    }
    __syncthreads();
  }

#pragma unroll
  for (int mt = 0; mt < 4; ++mt) {
#pragma unroll
    for (int nt = 0; nt < 4; ++nt) {
#pragma unroll
      for (int r = 0; r < 4; ++r) {
        const int m = m0 + wm * 64 + mt * 16 + l4 * 4 + r;
        const int n = n0 + wn * 64 + nt * 16 + l15;
        const float v = acc[mt][nt][r];
        if constexpr (EPI == 0) {
          const int b = m >> 11, t = m & (kT - 1);
          const int sec = n >> 10, nn = n & (kC - 1);
          const int h = nn >> 6, d = nn & 63;
          const size_t bh = (size_t)(b * kH + h);
          if (sec == 0)
            qb[(bh * kT + t) * kD + d] = f2bf(v);
          else if (sec == 1)
            kb[(bh * kT + t) * kD + d] = f2bf(v);
          else
            vT[(bh * kD + d) * kT + t] = f2bf(v);
        } else {
          out[(size_t)m * kC + n] = v;
        }
      }
    }
  }
}

// ---------------- flash attention (causal), swapped-QK, K-prefetch ----------------
// grid(x = bh, y = qt'); qt = 31 - y (LPT: long blocks first); XCD = slot%8 ~ bh%8
// clusters each head's K/V (512KB) into one XCD's L2.
__global__ __launch_bounds__(256, 4) void attn(const uint16_t* __restrict__ qb,
                                               const uint16_t* __restrict__ kb,
                                               const uint16_t* __restrict__ vT,
                                               uint16_t* __restrict__ y) {
  __shared__ char plds[8192];  // 4 waves x 2KB P slab
  const int lane = threadIdx.x & 63;
  const int wid = threadIdx.x >> 6;
  const int l15 = lane & 15, l4 = lane >> 4;
  const int bh = blockIdx.x;
  const int qt = (int)(gridDim.y - 1) - (int)blockIdx.y;
  const int q0 = qt * 64 + wid * 16;  // this wave's first q row
  const size_t base = (size_t)bh * kT * kD;
  const uint16_t* Q = qb + base;
  const uint16_t* Kp = kb + base;
  const uint16_t* Vt = vT + base;
  char* P = plds + wid * 2048;
  const int xr = (l15 & 7) << 4;

  // Q fragments (scaled by 1/sqrt(d)); B-operand of swapped QK
  bf16x8 qf[2];
#pragma unroll
  for (int ks = 0; ks < 2; ++ks) {
    bf16x8 t = *(const bf16x8*)(Q + (size_t)(q0 + l15) * kD + ks * 32 + l4 * 8);
#pragma unroll
    for (int i = 0; i < 8; ++i) t[i] = (__bf16)((float)t[i] * 0.125f);
    qf[ks] = t;
  }

  float m_ = -1e30f, l_ = 0.f;   // per-lane: q = q0 + l15
  f32x4 o[4];                    // O^T[d = nt*16 + l4*4 + r][q = l15]
#pragma unroll
  for (int nt = 0; nt < 4; ++nt) o[nt] = (f32x4){0.f, 0.f, 0.f, 0.f};

  const int nkt = (q0 + 15) / 64 + 1;

  // preload K fragments for tile 0 (A-operand: rows = kv index)
  bf16x8 kf[8];
#pragma unroll
  for (int nt = 0; nt < 4; ++nt)
#pragma unroll
    for (int ks = 0; ks < 2; ++ks)
      kf[nt * 2 + ks] = *(const bf16x8*)(Kp + (size_t)(nt * 16 + l15) * kD + ks * 32 + l4 * 8);

  for (int kt = 0; kt < nkt; ++kt) {
    const int k0 = kt * 64;
    // V fragment loads for current tile (A-operand of PV) — issue early,
    // latency hides under QK + softmax
    bf16x8 vf[8];
#pragma unroll
    for (int nt = 0; nt < 4; ++nt)
#pragma unroll
      for (int ks = 0; ks < 2; ++ks)
        vf[nt * 2 + ks] =
            *(const bf16x8*)(Vt + (size_t)(nt * 16 + l15) * kT + k0 + ks * 32 + l4 * 8);

    // S^T = K Q^T : s[nt][r] = S[q0+l15][k0 + nt*16 + l4*4 + r]
    f32x4 s[4] = {};
    __builtin_amdgcn_s_setprio(1);
#pragma unroll
    for (int ks = 0; ks < 2; ++ks)
#pragma unroll
      for (int nt = 0; nt < 4; ++nt)
        s[nt] = __builtin_amdgcn_mfma_f32_16x16x32_bf16(kf[nt * 2 + ks], qf[ks], s[nt], 0, 0, 0);
    __builtin_amdgcn_s_setprio(0);

    // prefetch K fragments for next tile (clamped re-read on last iter; unused)
    const int kn = (kt + 1 < nkt ? kt + 1 : kt) * 64;
#pragma unroll
    for (int nt = 0; nt < 4; ++nt)
#pragma unroll
      for (int ks = 0; ks < 2; ++ks)
        kf[nt * 2 + ks] =
            *(const bf16x8*)(Kp + (size_t)(kn + nt * 16 + l15) * kD + ks * 32 + l4 * 8);

    // causal mask: only the diagonal (last) tile needs it
    if (kt == nkt - 1) {
      const int qq = q0 + l15;
#pragma unroll
      for (int nt = 0; nt < 4; ++nt)
#pragma unroll
        for (int r = 0; r < 4; ++r)
          if (k0 + nt * 16 + l4 * 4 + r > qq) s[nt][r] = -1e30f;
    }

    // online softmax: lane owns full row slice; reduce across l4 groups (2 shuffles)
    float pm = -1e30f;
#pragma unroll
    for (int nt = 0; nt < 4; ++nt)
#pragma unroll
      for (int r = 0; r < 4; ++r) pm = fmaxf(pm, s[nt][r]);
    pm = fmaxf(pm, __shfl_xor(pm, 16));
    pm = fmaxf(pm, __shfl_xor(pm, 32));
    const float newm = fmaxf(m_, pm);
    const float sc = __expf(m_ - newm);
    m_ = newm;
    float ps = 0.f;
#pragma unroll
    for (int nt = 0; nt < 4; ++nt)
#pragma unroll
      for (int r = 0; r < 4; ++r) {
        const float p = __expf(s[nt][r] - newm);
        s[nt][r] = p;
        ps += p;
      }
    ps += __shfl_xor(ps, 16);
    ps += __shfl_xor(ps, 32);
    l_ = l_ * sc + ps;

    // P -> LDS (bf16, 8B packed, XOR-swizzled): row q=l15, col byte 2k
#pragma unroll
    for (int nt = 0; nt < 4; ++nt) {
      bf16x4 pk;
#pragma unroll
      for (int r = 0; r < 4; ++r) pk[r] = (__bf16)s[nt][r];
      *(bf16x4*)(P + l15 * 128 + ((nt * 32 + l4 * 8) ^ xr)) = pk;
    }
    asm volatile("s_waitcnt lgkmcnt(0)" ::: "memory");
    __builtin_amdgcn_sched_barrier(0);

    // rescale O
#pragma unroll
    for (int nt = 0; nt < 4; ++nt)
#pragma unroll
      for (int r = 0; r < 4; ++r) o[nt][r] *= sc;

    // O^T += V^T P^T
    bf16x8 pf[2];
#pragma unroll
    for (int ks = 0; ks < 2; ++ks)
      pf[ks] = *(const bf16x8*)(P + l15 * 128 + ((ks * 64 + l4 * 16) ^ xr));
    __builtin_amdgcn_s_setprio(1);
#pragma unroll
    for (int ks = 0; ks < 2; ++ks)
#pragma unroll
      for (int nt = 0; nt < 4; ++nt)
        o[nt] = __builtin_amdgcn_mfma_f32_16x16x32_bf16(vf[nt * 2 + ks], pf[ks], o[nt], 0, 0, 0);
    __builtin_amdgcn_s_setprio(0);
  }

  // epilogue: y[b, q, h*64 + d], packed 8B stores
  const int b = bh >> 4, h = bh & 15;
  const float inv = 1.0f / l_;
  const int q = q0 + l15;
#pragma unroll
  for (int nt = 0; nt < 4; ++nt) {
    bf16x4 yv;
#pragma unroll
    for (int r = 0; r < 4; ++r) yv[r] = (__bf16)(o[nt][r] * inv);
    *(bf16x4*)(y + ((size_t)(b * kT + q)) * kC + h * kD + nt * 16 + l4 * 4) = yv;
  }
}

extern "C" void kernel_launch(void* const* d_in, const int* in_sizes, int n_in,
                              void* d_out, int out_size, void* d_ws, size_t ws_size,
                              hipStream_t stream) {
  const float* x = (const float*)d_in[0];
  const float* wqkv = (const float*)d_in[1];
  const float* wproj = (const float*)d_in[2];
  const float* pe = (const float*)d_in[3];

  char* ws = (char*)d_ws;
  uint16_t* xp = (uint16_t*)(ws);                          // 8MB, reused as y after QKV
  uint16_t* wq = (uint16_t*)(ws + (size_t)(8u << 20));     // 6MB
  uint16_t* wp = (uint16_t*)(ws + (size_t)(14u << 20));    // 2MB
  uint16_t* qbuf = (uint16_t*)(ws + (size_t)(16u << 20));  // 8MB
  uint16_t* kbuf = (uint16_t*)(ws + (size_t)(24u << 20));  // 8MB
  uint16_t* vTb = (uint16_t*)(ws + (size_t)(32u << 20));   // 8MB (total 40MB)

  prep_xpe<<<dim3(kB * kT * kC / 4 / 256), 256, 0, stream>>>(x, pe, xp);
  cast_w<<<dim3(3 * kC * kC / 4 / 256), 256, 0, stream>>>(wqkv, wq);
  cast_w<<<dim3(kC * kC / 4 / 256), 256, 0, stream>>>(wproj, wp);

  // qkv = xp @ wqkv^T : M=4096, N=3072
  gemm_bt<0><<<dim3(32, 24), 256, 0, stream>>>(xp, wq, qbuf, kbuf, vTb, nullptr);

  // attention -> y (stored into xp buffer, [B,T,C] bf16)
  attn<<<dim3(kB * kH, kT / 64), 256, 0, stream>>>(qbuf, kbuf, vTb, xp);

  // out = y @ wproj^T : M=4096, N=1024, f32 out
  gemm_bt<1><<<dim3(32, 8), 256, 0, stream>>>(xp, wp, nullptr, nullptr, nullptr,
                                              (float*)d_out);
}

// Round 3
// 116.336 us; speedup vs baseline: 2.6998x; 1.9103x over previous
//
#include <hip/hip_runtime.h>
#include <cstdint>

typedef __bf16 bf16x8 __attribute__((ext_vector_type(8)));
typedef __bf16 bf16x4 __attribute__((ext_vector_type(4)));
typedef float  f32x4  __attribute__((ext_vector_type(4)));

static constexpr int kB = 2, kT = 2048, kC = 1024, kH = 16, kD = 64;
static constexpr int kK = 1024;  // GEMM inner dim (= kC)

__device__ __forceinline__ uint16_t f2bf(float f) {
  uint32_t u = __builtin_bit_cast(uint32_t, f);
  u += 0x7FFFu + ((u >> 16) & 1u);
  return (uint16_t)(u >> 16);
}

__device__ __forceinline__ void gl_lds16(const void* g, void* l) {
  __builtin_amdgcn_global_load_lds((__attribute__((address_space(1))) void*)(void*)g,
                                   (__attribute__((address_space(3))) void*)l, 16, 0, 0);
}

// ---------------- prep: xp = bf16(x + pe), w casts ----------------
__global__ __launch_bounds__(256) void prep_xpe(const float* __restrict__ x,
                                                const float* __restrict__ pe,
                                                uint16_t* __restrict__ xp) {
  const int i = blockIdx.x * 256 + threadIdx.x;  // over B*T*C/4
  const float4 xv = ((const float4*)x)[i];
  const int c4 = i & (kC / 4 - 1);
  const int t = (i / (kC / 4)) & (kT - 1);
  const float4 pv = ((const float4*)pe)[t * (kC / 4) + c4];
  ushort4 o;
  o.x = f2bf(xv.x + pv.x);
  o.y = f2bf(xv.y + pv.y);
  o.z = f2bf(xv.z + pv.z);
  o.w = f2bf(xv.w + pv.w);
  ((ushort4*)xp)[i] = o;
}

__global__ __launch_bounds__(256) void cast_w(const float* __restrict__ w,
                                              uint16_t* __restrict__ o) {
  const int i = blockIdx.x * 256 + threadIdx.x;
  const float4 v = ((const float4*)w)[i];
  ushort4 u;
  u.x = f2bf(v.x); u.y = f2bf(v.y); u.z = f2bf(v.z); u.w = f2bf(v.w);
  ((ushort4*)o)[i] = u;
}

// ---------------- GEMM: C = A[M,K] * W[N,K]^T, bf16 MFMA ----------------
template <int EPI>
__global__ __launch_bounds__(256) void gemm_bt(const uint16_t* __restrict__ A,
                                               const uint16_t* __restrict__ W,
                                               uint16_t* __restrict__ qb,
                                               uint16_t* __restrict__ kb,
                                               uint16_t* __restrict__ vT,
                                               float* __restrict__ out) {
  __shared__ char lds[32768];  // A tile 16KB | B tile 16KB
  const int lane = threadIdx.x & 63;
  const int wid = threadIdx.x >> 6;
  const int l15 = lane & 15, l4 = lane >> 4;
  const int wm = wid >> 1, wn = wid & 1;
  const int m0 = blockIdx.x * 128, n0 = blockIdx.y * 128;

  f32x4 acc[4][4] = {};

  for (int k0 = 0; k0 < kK; k0 += 64) {
#pragma unroll
    for (int j = 0; j < 4; ++j) {
      const int off = wid * 4096 + j * 1024 + lane * 16;
      const int row = off >> 7;
      const int colb = (off & 127) ^ ((row & 7) << 4);  // inverse-swizzled source
      gl_lds16((const char*)A + ((size_t)(m0 + row) * kK + k0) * 2 + colb,
               lds + wid * 4096 + j * 1024);
      gl_lds16((const char*)W + ((size_t)(n0 + row) * kK + k0) * 2 + colb,
               lds + 16384 + wid * 4096 + j * 1024);
    }
    __syncthreads();
#pragma unroll
    for (int ks = 0; ks < 2; ++ks) {
      bf16x8 af[4], bf_[4];
#pragma unroll
      for (int mt = 0; mt < 4; ++mt) {
        const int r = wm * 64 + mt * 16 + l15;
        const int cb = (l4 * 16 + ks * 64) ^ ((r & 7) << 4);
        af[mt] = *(const bf16x8*)(lds + r * 128 + cb);
      }
#pragma unroll
      for (int nt = 0; nt < 4; ++nt) {
        const int r = wn * 64 + nt * 16 + l15;
        const int cb = (l4 * 16 + ks * 64) ^ ((r & 7) << 4);
        bf_[nt] = *(const bf16x8*)(lds + 16384 + r * 128 + cb);
      }
#pragma unroll
      for (int mt = 0; mt < 4; ++mt)
#pragma unroll
        for (int nt = 0; nt < 4; ++nt)
          acc[mt][nt] = __builtin_amdgcn_mfma_f32_16x16x32_bf16(af[mt], bf_[nt],
                                                                acc[mt][nt], 0, 0, 0);
    }
    __syncthreads();
  }

#pragma unroll
  for (int mt = 0; mt < 4; ++mt) {
#pragma unroll
    for (int nt = 0; nt < 4; ++nt) {
#pragma unroll
      for (int r = 0; r < 4; ++r) {
        const int m = m0 + wm * 64 + mt * 16 + l4 * 4 + r;
        const int n = n0 + wn * 64 + nt * 16 + l15;
        const float v = acc[mt][nt][r];
        if constexpr (EPI == 0) {
          const int b = m >> 11, t = m & (kT - 1);
          const int sec = n >> 10, nn = n & (kC - 1);
          const int h = nn >> 6, d = nn & 63;
          const size_t bh = (size_t)(b * kH + h);
          if (sec == 0)
            qb[(bh * kT + t) * kD + d] = f2bf(v);
          else if (sec == 1)
            kb[(bh * kT + t) * kD + d] = f2bf(v);
          else
            vT[(bh * kD + d) * kT + t] = f2bf(v);
        } else {
          out[(size_t)m * kC + n] = v;
        }
      }
    }
  }
}

// ---------------- flash attention (causal), swapped-QK ----------------
// Cooperative double-buffered LDS staging of K/V tiles (counted vmcnt),
// deferred sum-reduce, defer-max (T13), exp2-domain softmax.
// grid(x = bh, y = qt'); qt = 31 - y (LPT); XCD ~ bh%8 clusters K/V in L2.
__global__ __launch_bounds__(256, 4) void attn(const uint16_t* __restrict__ qb,
                                               const uint16_t* __restrict__ kb,
                                               const uint16_t* __restrict__ vT,
                                               uint16_t* __restrict__ y) {
  // LDS: K[2] @ 0/8192 | V[2] @ 16384/24576 | P @ 32768 + wid*2048
  __shared__ __align__(1024) char lds[40960];
  const int lane = threadIdx.x & 63;
  const int wid = threadIdx.x >> 6;
  const int l15 = lane & 15, l4 = lane >> 4;
  const int bh = blockIdx.x;
  const int qt = (int)(gridDim.y - 1) - (int)blockIdx.y;
  const int q0 = qt * 64 + wid * 16;  // this wave's first q row
  const size_t base = (size_t)bh * kT * kD;
  const uint16_t* Q = qb + base;
  const uint16_t* Kp = kb + base;
  const uint16_t* Vt = vT + base;
  char* P = lds + 32768 + wid * 2048;
  const int xr = (l15 & 7) << 4;

  // Q fragments, scaled by log2(e)/sqrt(d) (exp2-domain softmax)
  bf16x8 qf[2];
#pragma unroll
  for (int ks = 0; ks < 2; ++ks) {
    bf16x8 t = *(const bf16x8*)(Q + (size_t)(q0 + l15) * kD + ks * 32 + l4 * 8);
#pragma unroll
    for (int i = 0; i < 8; ++i) t[i] = (__bf16)((float)t[i] * 0.1803368801f);
    qf[ks] = t;
  }

  float m_ = -1e30f, l_ = 0.f;   // per-lane; m_ kept row-uniform, l_ partial
  f32x4 o[4];                    // O^T[d = nt*16 + l4*4 + r][q = l15]
#pragma unroll
  for (int nt = 0; nt < 4; ++nt) o[nt] = (f32x4){0.f, 0.f, 0.f, 0.f};

  const int nkt = qt + 1;  // wave-uniform

  // cooperative stage of one K/V tile into buffer bi (4 gl_lds per wave)
  auto STAGE = [&](int bi, int k0) {
#pragma unroll
    for (int c = 0; c < 2; ++c) {
      const int call = wid * 2 + c;
      const int row = call * 8 + (lane >> 3);
      const int colb = (((lane & 7) ^ ((lane >> 3) & 7)) << 4);
      gl_lds16((const char*)Kp + ((size_t)(k0 + row) * kD) * 2 + colb,
               lds + bi * 8192 + call * 1024);
      gl_lds16((const char*)Vt + ((size_t)row * kT + k0) * 2 + colb,
               lds + 16384 + bi * 8192 + call * 1024);
    }
  };

  int cur = 0;
  STAGE(0, 0);
  for (int kt = 0; kt < nkt; ++kt) {
    const int k0 = kt * 64;
    const bool hasnext = (kt + 1 < nkt);
    if (hasnext) STAGE(cur ^ 1, k0 + 64);
    if (hasnext)
      asm volatile("s_waitcnt vmcnt(4)" ::: "memory");
    else
      asm volatile("s_waitcnt vmcnt(0)" ::: "memory");
    __builtin_amdgcn_s_barrier();
    asm volatile("" ::: "memory");

    const char* Kb = lds + cur * 8192;
    const char* Vb = lds + 16384 + cur * 8192;

    // S^T = K Q^T : s[nt][r] = S[q0+l15][k0 + nt*16 + l4*4 + r]  (log2-domain)
    f32x4 s[4] = {};
    __builtin_amdgcn_s_setprio(1);
#pragma unroll
    for (int ks = 0; ks < 2; ++ks)
#pragma unroll
      for (int nt = 0; nt < 4; ++nt) {
        const bf16x8 kf =
            *(const bf16x8*)(Kb + (nt * 16 + l15) * 128 + ((ks * 64 + l4 * 16) ^ xr));
        s[nt] = __builtin_amdgcn_mfma_f32_16x16x32_bf16(kf, qf[ks], s[nt], 0, 0, 0);
      }
    __builtin_amdgcn_s_setprio(0);

    // causal mask: only the diagonal (last) tile needs it
    if (kt == nkt - 1) {
      const int qq = q0 + l15;
#pragma unroll
      for (int nt = 0; nt < 4; ++nt)
#pragma unroll
        for (int r = 0; r < 4; ++r)
          if (k0 + nt * 16 + l4 * 4 + r > qq) s[nt][r] = -1e30f;
    }

    // online softmax, defer-max: skip cross-lane reduce + rescale when bounded
    float pm = s[0][0];
#pragma unroll
    for (int nt = 0; nt < 4; ++nt)
#pragma unroll
      for (int r = 0; r < 4; ++r) pm = fmaxf(pm, s[nt][r]);
    if (!__all(pm <= m_ + 11.0f)) {
      float rm = fmaxf(pm, __shfl_xor(pm, 16));
      rm = fmaxf(rm, __shfl_xor(rm, 32));
      const float newm = fmaxf(m_, rm);
      const float sc = exp2f(m_ - newm);
      m_ = newm;
      l_ *= sc;
#pragma unroll
      for (int nt = 0; nt < 4; ++nt)
#pragma unroll
        for (int r = 0; r < 4; ++r) o[nt][r] *= sc;
    }
    float ps = 0.f;
#pragma unroll
    for (int nt = 0; nt < 4; ++nt)
#pragma unroll
      for (int r = 0; r < 4; ++r) {
        const float p = exp2f(s[nt][r] - m_);
        s[nt][r] = p;
        ps += p;
      }
    l_ += ps;  // per-lane partial; reduced across l4 in epilogue

    // P -> LDS (bf16, 8B packed, XOR-swizzled): row q=l15, col byte 2k
#pragma unroll
    for (int nt = 0; nt < 4; ++nt) {
      bf16x4 pk;
#pragma unroll
      for (int r = 0; r < 4; ++r) pk[r] = (__bf16)s[nt][r];
      *(bf16x4*)(P + l15 * 128 + ((nt * 32 + l4 * 8) ^ xr)) = pk;
    }
    asm volatile("s_waitcnt lgkmcnt(0)" ::: "memory");
    __builtin_amdgcn_sched_barrier(0);

    // O^T += V^T P^T
    bf16x8 pf[2];
#pragma unroll
    for (int ks = 0; ks < 2; ++ks)
      pf[ks] = *(const bf16x8*)(P + l15 * 128 + ((ks * 64 + l4 * 16) ^ xr));
    __builtin_amdgcn_s_setprio(1);
#pragma unroll
    for (int ks = 0; ks < 2; ++ks)
#pragma unroll
      for (int nt = 0; nt < 4; ++nt) {
        const bf16x8 vf =
            *(const bf16x8*)(Vb + (nt * 16 + l15) * 128 + ((ks * 64 + l4 * 16) ^ xr));
        o[nt] = __builtin_amdgcn_mfma_f32_16x16x32_bf16(vf, pf[ks], o[nt], 0, 0, 0);
      }
    __builtin_amdgcn_s_setprio(0);

    __builtin_amdgcn_s_barrier();  // all waves done with buf[cur] before re-stage
    asm volatile("" ::: "memory");
    cur ^= 1;
  }

  // epilogue: reduce l_ across the 4 lanes of each row, then store
  l_ += __shfl_xor(l_, 16);
  l_ += __shfl_xor(l_, 32);
  const float inv = 1.0f / l_;
  const int b = bh >> 4, h = bh & 15;
  const int q = q0 + l15;
#pragma unroll
  for (int nt = 0; nt < 4; ++nt) {
    bf16x4 yv;
#pragma unroll
    for (int r = 0; r < 4; ++r) yv[r] = (__bf16)(o[nt][r] * inv);
    *(bf16x4*)(y + ((size_t)(b * kT + q)) * kC + h * kD + nt * 16 + l4 * 4) = yv;
  }
}

extern "C" void kernel_launch(void* const* d_in, const int* in_sizes, int n_in,
                              void* d_out, int out_size, void* d_ws, size_t ws_size,
                              hipStream_t stream) {
  const float* x = (const float*)d_in[0];
  const float* wqkv = (const float*)d_in[1];
  const float* wproj = (const float*)d_in[2];
  const float* pe = (const float*)d_in[3];

  char* ws = (char*)d_ws;
  uint16_t* xp = (uint16_t*)(ws);                          // 8MB, reused as y after QKV
  uint16_t* wq = (uint16_t*)(ws + (size_t)(8u << 20));     // 6MB
  uint16_t* wp = (uint16_t*)(ws + (size_t)(14u << 20));    // 2MB
  uint16_t* qbuf = (uint16_t*)(ws + (size_t)(16u << 20));  // 8MB
  uint16_t* kbuf = (uint16_t*)(ws + (size_t)(24u << 20));  // 8MB
  uint16_t* vTb = (uint16_t*)(ws + (size_t)(32u << 20));   // 8MB (total 40MB)

  prep_xpe<<<dim3(kB * kT * kC / 4 / 256), 256, 0, stream>>>(x, pe, xp);
  cast_w<<<dim3(3 * kC * kC / 4 / 256), 256, 0, stream>>>(wqkv, wq);
  cast_w<<<dim3(kC * kC / 4 / 256), 256, 0, stream>>>(wproj, wp);

  // qkv = xp @ wqkv^T : M=4096, N=3072
  gemm_bt<0><<<dim3(32, 24), 256, 0, stream>>>(xp, wq, qbuf, kbuf, vTb, nullptr);

  // attention -> y (stored into xp buffer, [B,T,C] bf16)
  attn<<<dim3(kB * kH, kT / 64), 256, 0, stream>>>(qbuf, kbuf, vTb, xp);

  // out = y @ wproj^T : M=4096, N=1024, f32 out
  gemm_bt<1><<<dim3(32, 8), 256, 0, stream>>>(xp, wp, nullptr, nullptr, nullptr,
                                              (float*)d_out);
}